// Round 10
// baseline (98.802 us; speedup 1.0000x reference)
//
#include <hip/hip_runtime.h>
#include <hip/hip_bf16.h>

#define N 1024
#define F 32
#define H 64
#define EA 8

typedef __attribute__((ext_vector_type(8))) short bf16x8;    // 8 bf16 in 4 VGPRs
typedef __attribute__((ext_vector_type(16))) float f32x16;   // MFMA C/D

union FragAB { bf16x8 v; unsigned u[4]; };

// pack two f32 -> one u32 (bf16(a) lo, bf16(b) hi), RNE
__device__ __forceinline__ unsigned pk(float a, float b) {
    union { __hip_bfloat162 h; unsigned u; } c;
    c.h = __float22bfloat162_rn(float2{a, b});
    return c.u;
}

// Kernel 1: computes sv=b+X(Ws-Wd), nb=X·Wd; emits
//   svq[v][ln] = {pk(sv[v,ln],1e30), pk(sv[v,ln+32],1e30)}  (uint2, kernel2 k8/k9 slot)
//   nbL        = nb rearranged into MFMA C-layout (16 contiguous f32 per lane)
//   out        = 0
// One wave per v; lane = h.
__global__ __launch_bounds__(256) void precompute_terms(
    const float* __restrict__ X, const float* __restrict__ W, const float* __restrict__ b,
    uint2* __restrict__ svq, float* __restrict__ nbL, float* __restrict__ out)
{
    const int lane = threadIdx.x & 63;
    const int wid  = threadIdx.x >> 6;
    const int v    = blockIdx.x * 4 + wid;

    float4 xr[8];
    const float4* xp = (const float4*)(X + (size_t)v * F);
#pragma unroll
    for (int i = 0; i < 8; ++i) xr[i] = xp[i];
    const float* xf = (const float*)xr;

    float s = b[lane];
    float n = 0.f;
#pragma unroll
    for (int f = 0; f < F; ++f) {
        float ws = W[f * H + lane];
        float wd = W[(F + f) * H + lane];
        s = fmaf(xf[f], ws - wd, s);
        n = fmaf(xf[f], wd, n);
    }
    out[v * H + lane] = 0.f;

    // svq: lane<32 packs its own (lo) and lane+32's (hi) value
    const unsigned p  = pk(s, 1e30f);
    const unsigned ph = __shfl_down(p, 32);
    if (lane < 32) svq[v * 32 + lane] = uint2{p, ph};

    // nbL scatter: value for C-reg r of lane l, half hh, tile t
    //   row = v&31 -> lg=(row>>2)&1, r=(row&3)+4*(row>>3); l=(h&31)|(lg<<5)
    const int t  = v >> 5, w5 = v & 31;
    const int lg = (w5 >> 2) & 1;
    const int r  = (w5 & 3) + 4 * (w5 >> 3);
    const int hh = lane >> 5;
    const int l  = (lane & 31) | (lg << 5);
    nbL[(((t * 2 + hh) * 64 + l) << 4) + r] = n;
}

// Kernel 2: MFMA 32x32x16 bf16 (R9 structure + VMEM diet).
//   k=0..7 : E[v,w,e] x We[e,h];  k=8: 1.0 x sv[v,h];  k=9: (mask?0:-1) x 1e30
//   C-init = nbL (pre-arranged C-layout, 8 coalesced dwordx4).
// Loads exec-masked to consuming half-wave: E/W -> lanes 0-31, A/svq -> lanes 32-63.
// E depth-2 register prefetch, compiler-scheduled vmcnt. Partials via
// conflict-free ds_write, block reduce, fan-in-8 device atomics.
__global__ __launch_bounds__(256, 4) void edge_mfma(
    const int* __restrict__ A, const float* __restrict__ Edge, const float* __restrict__ W,
    const uint2* __restrict__ svq, const float* __restrict__ nbL, float* __restrict__ out)
{
    const int lane = threadIdx.x & 63;
    const int wid  = threadIdx.x >> 6;
    const int lg   = lane >> 5;          // k-octet group (0: k=0-7, 1: k=8-15)
    const int ln   = lane & 31;          // A-row / B,C-col index
    const int wq   = blockIdx.x & 7;
    const int vch  = blockIdx.x >> 3;
    const int wbase = wq * 128 + wid * 32;
    const int vbase = vch * 8;
    const int t     = wq * 4 + wid;      // 32-w tile index

    __shared__ float part[4][2][8][64];  // [wid][lg][vi][col] = 16 KB

    // --- A-mask + packed-sv preloads, exec-masked to lg1 (the consuming lanes) ---
    int am[8]; uint2 sq[8];
    if (lg) {
        const int* ap = A + (size_t)vbase * N + wbase + ln;
#pragma unroll
        for (int vi = 0; vi < 8; ++vi) {
            am[vi] = ap[(size_t)vi * N];
            sq[vi] = svq[(vbase + vi) * 32 + ln];
        }
    }

    // --- E depth-2 prefetch ring, exec-masked to lg0 ---
    const float4* ep = (const float4*)(Edge + ((size_t)vbase * N + wbase + ln) * EA);
    float4 eA[2], eB[2];
    if (!lg) {
        eA[0] = ep[0];    eB[0] = ep[1];
        eA[1] = ep[2048]; eB[1] = ep[2049];
    }

    // --- B static (We packed), exec-masked to lg0; lg1 slots zero ---
    FragAB bfr[2];
#pragma unroll
    for (int half = 0; half < 2; ++half)
#pragma unroll
        for (int q = 0; q < 4; ++q) bfr[half].u[q] = 0u;
    if (!lg) {
#pragma unroll
        for (int half = 0; half < 2; ++half) {
            const int n = half * 32 + ln;
#pragma unroll
            for (int q = 0; q < 4; ++q)
                bfr[half].u[q] = pk(W[(2 * F + 2 * q) * H + n], W[(2 * F + 2 * q + 1) * H + n]);
        }
    }

    // --- C-init from nbL: 16 contiguous floats per lane per half (4 dwordx4) ---
    f32x16 cnb[2];
#pragma unroll
    for (int hh = 0; hh < 2; ++hh) {
        const float4* cp = (const float4*)(nbL + (((t * 2 + hh) * 64 + lane) << 4));
#pragma unroll
        for (int q = 0; q < 4; ++q) {
            const float4 x = cp[q];
            cnb[hh][4 * q + 0] = x.x; cnb[hh][4 * q + 1] = x.y;
            cnb[hh][4 * q + 2] = x.z; cnb[hh][4 * q + 3] = x.w;
        }
    }

#pragma unroll
    for (int vi = 0; vi < 8; ++vi) {
        const float4 ca = eA[vi & 1];
        const float4 cb = eB[vi & 1];
        if (vi < 6 && !lg) {
            eA[vi & 1] = ep[(vi + 2) * 2048];
            eB[vi & 1] = ep[(vi + 2) * 2048 + 1];
        }

        FragAB afr;
        const unsigned mpat = am[vi] ? 0x00003f80u : 0xbf803f80u;  // k8=1.0, k9=0/-1
        afr.u[0] = lg ? mpat : pk(ca.x, ca.y);
        afr.u[1] = lg ? 0u : pk(ca.z, ca.w);
        afr.u[2] = lg ? 0u : pk(cb.x, cb.y);
        afr.u[3] = lg ? 0u : pk(cb.z, cb.w);

        FragAB b0 = bfr[0], b1 = bfr[1];
        if (lg) { b0.u[0] = sq[vi].x; b1.u[0] = sq[vi].y; }   // {sv, 1e30} slot

        const f32x16 d0 = __builtin_amdgcn_mfma_f32_32x32x16_bf16(afr.v, b0.v, cnb[0], 0, 0, 0);
        const f32x16 d1 = __builtin_amdgcn_mfma_f32_32x32x16_bf16(afr.v, b1.v, cnb[1], 0, 0, 0);

        float p0 = 0.f, p1 = 0.f;
#pragma unroll
        for (int r = 0; r < 16; ++r) {
            p0 += fmaxf(d0[r], 0.f);
            p1 += fmaxf(d1[r], 0.f);
        }
        part[wid][lg][vi][ln]      = p0;   // lanes L and L+32 same bank: 2-way, free
        part[wid][lg][vi][32 + ln] = p1;
    }

    __syncthreads();
#pragma unroll
    for (int i = threadIdx.x; i < 512; i += 256) {
        const int vi = i >> 6, h = i & 63;
        float s = 0.f;
#pragma unroll
        for (int w4 = 0; w4 < 4; ++w4)
#pragma unroll
            for (int g = 0; g < 2; ++g) s += part[w4][g][vi][h];
        unsafeAtomicAdd(&out[(size_t)(vbase + vi) * H + h], s);
    }
}

extern "C" void kernel_launch(void* const* d_in, const int* in_sizes, int n_in,
                              void* d_out, int out_size, void* d_ws, size_t ws_size,
                              hipStream_t stream) {
    const int*   A    = (const int*)d_in[0];
    const float* X    = (const float*)d_in[1];
    const float* Edge = (const float*)d_in[2];
    const float* W    = (const float*)d_in[3];
    const float* b    = (const float*)d_in[4];
    float* out = (float*)d_out;

    uint2* svq = (uint2*)d_ws;                       // N*32 uint2 = 256 KB
    float* nbL = (float*)((char*)d_ws + N * 32 * sizeof(uint2));  // 64K floats = 256 KB

    precompute_terms<<<dim3(256), dim3(256), 0, stream>>>(X, W, b, svq, nbL, out);
    edge_mfma<<<dim3(1024), dim3(256), 0, stream>>>(A, Edge, W, svq, nbL, out);
}

// Round 12
// 89.053 us; speedup vs baseline: 1.1095x; 1.1095x over previous
//
#include <hip/hip_runtime.h>
#include <hip/hip_bf16.h>

#define N 1024
#define F 32
#define H 64
#define EA 8

typedef __attribute__((ext_vector_type(8))) short bf16x8;    // 8 bf16 in 4 VGPRs
typedef __attribute__((ext_vector_type(16))) float f32x16;   // MFMA C/D

union FragAB { bf16x8 v; unsigned u[4]; };

// pack two f32 -> one u32 (bf16(a) lo, bf16(b) hi), RNE
__device__ __forceinline__ unsigned pk(float a, float b) {
    union { __hip_bfloat162 h; unsigned u; } c;
    c.h = __float22bfloat162_rn(float2{a, b});
    return c.u;
}

// Kernel 1: sv[v,h] = b[h] + sum_f X[v,f]*(W[f,h]-W[32+f,h]); nb[v,h] = sum_f X[v,f]*W[32+f,h]
// Also zeroes out[]. One wave per v; lane = h.
__global__ __launch_bounds__(256) void precompute_terms(
    const float* __restrict__ X, const float* __restrict__ W, const float* __restrict__ b,
    float* __restrict__ sv, float* __restrict__ nb, float* __restrict__ out)
{
    const int lane = threadIdx.x & 63;
    const int wid  = threadIdx.x >> 6;
    const int v    = blockIdx.x * 4 + wid;

    float4 xr[8];
    const float4* xp = (const float4*)(X + (size_t)v * F);
#pragma unroll
    for (int i = 0; i < 8; ++i) xr[i] = xp[i];
    const float* xf = (const float*)xr;

    float s = b[lane];
    float n = 0.f;
#pragma unroll
    for (int f = 0; f < F; ++f) {
        float ws = W[f * H + lane];
        float wd = W[(F + f) * H + lane];
        s = fmaf(xf[f], ws - wd, s);
        n = fmaf(xf[f], wd, n);
    }
    const int idx = v * H + lane;
    sv[idx]  = s;
    nb[idx]  = n;
    out[idx] = 0.f;
}

// Kernel 2: MFMA 32x32x16 bf16 (R11 structure; epilogue atomics hardened to
// device-scope atomicAdd — unsafeAtomicAdd is the suspected silent-drop source
// of R11's post-timing divergence).
//   k=0..7 : E[v,w,e] x We[e,h];  k=8: 1.0 x sv[v,h];  k=9: (mask?0:-1) x 1e30
//   C-init = nb[w,h] in C-layout (v-invariant). Wave = 32-w tile x 64 h, loops 4 v.
// E in registers (depth-2 prefetch ring, compiler-scheduled vmcnt); A/sv batched
// up front; all loads issued by all lanes (branch-free schedule). Partials via
// conflict-free ds_write, block reduce, fan-in-8 device atomics.
// Grid: 256 v-chunks x 8 w-quads = 2048 blocks -> 8 blocks/CU, 8 waves/SIMD.
__global__ __launch_bounds__(256, 4) void edge_mfma(
    const int* __restrict__ A, const float* __restrict__ Edge, const float* __restrict__ W,
    const float* __restrict__ sv, const float* __restrict__ nb, float* __restrict__ out)
{
    const int lane = threadIdx.x & 63;
    const int wid  = threadIdx.x >> 6;
    const int lg   = lane >> 5;          // k-octet group (0: k=0-7, 1: k=8-15)
    const int ln   = lane & 31;          // A-row / B,C-col index
    const int wq   = blockIdx.x & 7;
    const int vch  = blockIdx.x >> 3;
    const int wbase = wq * 128 + wid * 32;
    const int vbase = vch * 4;

    __shared__ float part[4][2][4][64];  // [wid][lg][vi][col] = 8 KB

    // --- batched preloads: A-mask + sv for all 4 vi (latency hidden by setup) ---
    const int* ap = A + (size_t)vbase * N + wbase + ln;
    int am[4]; float s0v[4], s1v[4];
#pragma unroll
    for (int vi = 0; vi < 4; ++vi) {
        am[vi]  = ap[(size_t)vi * N];
        s0v[vi] = sv[(size_t)(vbase + vi) * H + ln];
        s1v[vi] = sv[(size_t)(vbase + vi) * H + 32 + ln];
    }

    // E row pointer for this lane's w (=wbase+ln); v-stride = N*EA/4 = 2048 float4
    const float4* ep = (const float4*)(Edge + ((size_t)vbase * N + wbase + ln) * EA);
    // depth-2 register prefetch ring
    float4 eA[2], eB[2];
    eA[0] = ep[0];    eB[0] = ep[1];
    eA[1] = ep[2048]; eB[1] = ep[2049];

    // B static: We[e][h] packed in k-octet 0; zeros in k-octet 1
    FragAB bfr[2];
#pragma unroll
    for (int half = 0; half < 2; ++half) {
        const int n = half * 32 + ln;
#pragma unroll
        for (int q = 0; q < 4; ++q) {
            unsigned we = pk(W[(2 * F + 2 * q) * H + n], W[(2 * F + 2 * q + 1) * H + n]);
            bfr[half].u[q] = (lg == 0) ? we : 0u;
        }
    }

    // C-init = nb in MFMA C-layout: row=(r&3)+8*(r>>2)+4*lg, col=ln(+32*half)
    f32x16 cnb[2];
#pragma unroll
    for (int half = 0; half < 2; ++half)
#pragma unroll
        for (int r = 0; r < 16; ++r) {
            const int row = (r & 3) + 8 * (r >> 2) + 4 * lg;
            cnb[half][r] = nb[(size_t)(wbase + row) * H + half * 32 + ln];
        }

#pragma unroll
    for (int vi = 0; vi < 4; ++vi) {
        const float4 ca = eA[vi & 1];
        const float4 cb = eB[vi & 1];
        if (vi < 2) {
            eA[vi & 1] = ep[(vi + 2) * 2048];
            eB[vi & 1] = ep[(vi + 2) * 2048 + 1];
        }

        FragAB afr;
        const unsigned mpat = am[vi] ? 0x00003f80u : 0xbf803f80u;  // k8=1.0, k9=0/-1
        afr.u[0] = (lg == 0) ? pk(ca.x, ca.y) : mpat;
        afr.u[1] = (lg == 0) ? pk(ca.z, ca.w) : 0u;
        afr.u[2] = (lg == 0) ? pk(cb.x, cb.y) : 0u;
        afr.u[3] = (lg == 0) ? pk(cb.z, cb.w) : 0u;

        FragAB b0 = bfr[0], b1 = bfr[1];
        if (lg) { b0.u[0] = pk(s0v[vi], 1e30f); b1.u[0] = pk(s1v[vi], 1e30f); }

        const f32x16 d0 = __builtin_amdgcn_mfma_f32_32x32x16_bf16(afr.v, b0.v, cnb[0], 0, 0, 0);
        const f32x16 d1 = __builtin_amdgcn_mfma_f32_32x32x16_bf16(afr.v, b1.v, cnb[1], 0, 0, 0);

        float p0 = 0.f, p1 = 0.f;
#pragma unroll
        for (int r = 0; r < 16; ++r) {
            p0 += fmaxf(d0[r], 0.f);
            p1 += fmaxf(d1[r], 0.f);
        }
        part[wid][lg][vi][ln]      = p0;   // lanes L and L+32 same bank: 2-way, free
        part[wid][lg][vi][32 + ln] = p1;
    }

    __syncthreads();
    {
        const int i  = threadIdx.x;
        const int vi = i >> 6, h = i & 63;
        float s = 0.f;
#pragma unroll
        for (int w4 = 0; w4 < 4; ++w4)
#pragma unroll
            for (int g = 0; g < 2; ++g) s += part[w4][g][vi][h];
        atomicAdd(&out[(size_t)(vbase + vi) * H + h], s);   // device-scope, safe
    }
}

extern "C" void kernel_launch(void* const* d_in, const int* in_sizes, int n_in,
                              void* d_out, int out_size, void* d_ws, size_t ws_size,
                              hipStream_t stream) {
    const int*   A    = (const int*)d_in[0];
    const float* X    = (const float*)d_in[1];
    const float* Edge = (const float*)d_in[2];
    const float* W    = (const float*)d_in[3];
    const float* b    = (const float*)d_in[4];
    float* out = (float*)d_out;

    float* sv = (float*)d_ws;
    float* nb = sv + N * H;

    precompute_terms<<<dim3(256), dim3(256), 0, stream>>>(X, W, b, sv, nb, out);
    edge_mfma<<<dim3(2048), dim3(256), 0, stream>>>(A, Edge, W, sv, nb, out);
}